// Round 5
// baseline (665.107 us; speedup 1.0000x reference)
//
#include <hip/hip_runtime.h>
#include <hip/hip_bf16.h>
#include <math.h>

#define LN_EPS 1e-5f

typedef short short8 __attribute__((ext_vector_type(8)));
typedef float floatx4 __attribute__((ext_vector_type(4)));

__device__ inline unsigned short f2bf(float f) {
    unsigned int u = __float_as_uint(f);
    u += 0x7fff + ((u >> 16) & 1);   // round-to-nearest-even
    return (unsigned short)(u >> 16);
}

__device__ inline void gl_lds16(const unsigned short* g, unsigned short* l) {
    __builtin_amdgcn_global_load_lds(
        (__attribute__((address_space(1))) const void*)g,
        (__attribute__((address_space(3))) void*)l, 16, 0, 0);
}

// overflow-safe tanh-approx GELU (max abs err ~1e-3 vs exact)
__device__ inline float gelu_f(float v) {
    float u2 = 2.0f * v * (0.7978845608f + 0.0356774081f * v * v);
    float t  = 1.0f - 2.0f / (__expf(u2) + 1.0f);
    return 0.5f * v * (1.0f + t);
}

// ---------------------------------------------------------------------------
// bf16 MFMA GEMM, 128x128 tile, BK=64, hybrid operand paths:
//   A: staged global->LDS via global_load_lds (shared by wn waves)
//   B: DIRECT global->VGPR fragments, ping-pong prefetched one iter ahead
//      (escapes the barrier vmcnt(0) drain; overlaps compute).
//  A: MxK row-major bf16.   B: NxK row-major bf16 (B^T given).
// Swapped-operand MFMA: mfma(bfr, afr) -> lane holds 4 consecutive out cols.
//  EPI: 2 = +bias, GELU, bf16 out
//       3 = *scale + mask[batch][col], bf16 out       (QK^T scores)
//       4 = +resid[batch], fp32 out                   (PV: x + attn)
//       5 = +bias +resid, fp32 out                    (FFN2: h + ffn)
// M,N mult of 128; K mult of 128.
// ---------------------------------------------------------------------------
template<int EPI>
__global__ __launch_bounds__(256) void gemm_bt(
    const unsigned short* __restrict__ A, const unsigned short* __restrict__ B,
    const float* __restrict__ bias, const float* __restrict__ resid,
    void* __restrict__ Cptr,
    int M, int N, int K, long sA, long sB, long sC, long sBias, float scale)
{
    __shared__ unsigned short lds_a[2 * 128 * 32];   // two k-half tiles [m][k]

    const int tid  = threadIdx.x;
    const int lane = tid & 63;
    const int wave = tid >> 6;
    const int quad = lane >> 4;
    const int l16  = lane & 15;
    const int wm = wave >> 1, wn = wave & 1;
    const int tile_m = blockIdx.y * 128;
    const int tile_n = blockIdx.x * 128;
    const int batch  = blockIdx.z;

    const unsigned short* Ab = A + (size_t)batch * sA;
    const unsigned short* Bb = B + (size_t)batch * sB;

    // --- A staging (wave-uniform base + lane*16B) ---
    const int srow = wave * 16 + (lane >> 2);
    const int scol = (lane & 3) * 8;
    const unsigned short* gA0 = Ab + (size_t)(tile_m + srow) * K + scol;
    const unsigned short* gA1 = Ab + (size_t)(tile_m + 64 + srow) * K + scol;
    unsigned short* lA0 = &lds_a[wave * 512 + lane * 8];
    unsigned short* lA1 = &lds_a[2048 + wave * 512 + lane * 8];

    // --- B direct-load fragment pointers (per-lane) ---
    const unsigned short* gB[4];
#pragma unroll
    for (int j = 0; j < 4; j++)
        gB[j] = Bb + (size_t)(tile_n + wn * 64 + j * 16 + l16) * K + quad * 8;

    floatx4 acc[4][4];
    const floatx4 zero = {0.f, 0.f, 0.f, 0.f};
#pragma unroll
    for (int i = 0; i < 4; i++)
#pragma unroll
        for (int j = 0; j < 4; j++) acc[i][j] = zero;

    short8 b0[2][4], b1[2][4];
#pragma unroll
    for (int h = 0; h < 2; h++)
#pragma unroll
        for (int j = 0; j < 4; j++)
            b0[h][j] = *(const short8*)(gB[j] + h * 32);

    // body: stage A(k0) into LDS, prefetch B(k0+64) into bnext, compute bcur
    auto body = [&](short8 bcur[2][4], short8 bnext[2][4], int k0) {
        __syncthreads();                 // prev-iter LDS reads complete
        gl_lds16(gA0 + k0,      lA0);
        gl_lds16(gA1 + k0,      lA1);
        gl_lds16(gA0 + k0 + 32, lA0 + 4096);
        gl_lds16(gA1 + k0 + 32, lA1 + 4096);
        __syncthreads();                 // drain A staging (16KB only)
        if (k0 + 64 < K) {
#pragma unroll
            for (int h = 0; h < 2; h++)
#pragma unroll
                for (int j = 0; j < 4; j++)
                    bnext[h][j] = *(const short8*)(gB[j] + k0 + 64 + h * 32);
        }
#pragma unroll
        for (int h = 0; h < 2; h++) {
            short8 afr[4];
#pragma unroll
            for (int i = 0; i < 4; i++)
                afr[i] = *(const short8*)
                    &lds_a[h * 4096 + (wm * 64 + i * 16 + l16) * 32 + quad * 8];
#pragma unroll
            for (int i = 0; i < 4; i++)
#pragma unroll
                for (int j = 0; j < 4; j++)
                    acc[i][j] = __builtin_amdgcn_mfma_f32_16x16x32_bf16(
                        bcur[h][j], afr[i], acc[i][j], 0, 0, 0);
        }
    };

    for (int k0 = 0; k0 < K; k0 += 128) {
        body(b0, b1, k0);
        body(b1, b0, k0 + 64);
    }

    // ---- epilogue: per frag, lane holds row (l16) x 4 consecutive cols ----
#pragma unroll
    for (int i = 0; i < 4; i++) {
        const int row = tile_m + wm * 64 + i * 16 + l16;
#pragma unroll
        for (int j = 0; j < 4; j++) {
            const int colb = tile_n + wn * 64 + j * 16 + quad * 4;
            float v[4];
#pragma unroll
            for (int r = 0; r < 4; r++) v[r] = acc[i][j][r];

            if (EPI == 3) {
                float4 mv = *(const float4*)&bias[(size_t)batch * sBias + colb];
                v[0] = v[0] * scale + mv.x;  v[1] = v[1] * scale + mv.y;
                v[2] = v[2] * scale + mv.z;  v[3] = v[3] * scale + mv.w;
            }
            if (EPI == 2 || EPI == 5) {
                float4 bv = *(const float4*)&bias[colb];
                v[0] += bv.x; v[1] += bv.y; v[2] += bv.z; v[3] += bv.w;
            }
            if (EPI == 2) {
#pragma unroll
                for (int r = 0; r < 4; r++) v[r] = gelu_f(v[r]);
            }
            if (EPI == 4 || EPI == 5) {
                float4 rv = *(const float4*)&resid[(size_t)batch * sC +
                                                   (size_t)row * N + colb];
                v[0] += rv.x; v[1] += rv.y; v[2] += rv.z; v[3] += rv.w;
            }

            if (EPI == 2 || EPI == 3) {
                unsigned short* C = (unsigned short*)Cptr + (size_t)batch * sC;
                ushort4 h4;
                h4.x = f2bf(v[0]); h4.y = f2bf(v[1]);
                h4.z = f2bf(v[2]); h4.w = f2bf(v[3]);
                *(ushort4*)(C + (size_t)row * N + colb) = h4;
            } else {
                float* C = (float*)Cptr + (size_t)batch * sC;
                float4 f4 = {v[0], v[1], v[2], v[3]};
                *(float4*)(C + (size_t)row * N + colb) = f4;
            }
        }
    }
}

// ---------------------------------------------------------------------------
// x prep: read x [S,D] fp32 once -> xb [S,D] bf16 AND xTb [D,S] bf16.
// ---------------------------------------------------------------------------
__global__ __launch_bounds__(256) void x_prep_kernel(
    const float* __restrict__ in, unsigned short* __restrict__ straight,
    unsigned short* __restrict__ transposed, int R, int C, long sIn)
{
    __shared__ float tile[32][33];
    const int tc = blockIdx.x * 32, tr = blockIdx.y * 32;
    const float* src = in + (size_t)blockIdx.z * sIn;
    unsigned short* dstS = straight   + (size_t)blockIdx.z * sIn;
    unsigned short* dstT = transposed + (size_t)blockIdx.z * sIn;
    const int tx = threadIdx.x & 31, ty = threadIdx.x >> 5;
#pragma unroll
    for (int i = 0; i < 4; i++) {
        float val = src[(size_t)(tr + ty + i * 8) * C + tc + tx];
        tile[ty + i * 8][tx] = val;
        dstS[(size_t)(tr + ty + i * 8) * C + tc + tx] = f2bf(val);
    }
    __syncthreads();
#pragma unroll
    for (int i = 0; i < 4; i++)
        dstT[(size_t)(tc + ty + i * 8) * R + tr + tx] = f2bf(tile[tx][ty + i * 8]);
}

// ---------------------------------------------------------------------------
__global__ __launch_bounds__(256) void transpose_cvt_kernel(
    const float* __restrict__ in, unsigned short* __restrict__ out, int R, int C)
{
    __shared__ float tile[32][33];
    const int tc = blockIdx.x * 32, tr = blockIdx.y * 32;
    const int tx = threadIdx.x & 31, ty = threadIdx.x >> 5;
#pragma unroll
    for (int i = 0; i < 4; i++)
        tile[ty + i * 8][tx] = in[(size_t)(tr + ty + i * 8) * C + tc + tx];
    __syncthreads();
#pragma unroll
    for (int i = 0; i < 4; i++)
        out[(size_t)(tc + ty + i * 8) * R + tr + tx] = f2bf(tile[tx][ty + i * 8]);
}

// ---------------------------------------------------------------------------
// Pure row softmax over S=2048: bf16 in (scale+mask pre-applied) -> bf16 out.
// ---------------------------------------------------------------------------
__global__ __launch_bounds__(256) void softmax_bf16_kernel(
    const unsigned short* __restrict__ scores, unsigned short* __restrict__ probs,
    int S)
{
    __shared__ float red[4];
    const int row = blockIdx.x;
    const unsigned short* p = scores + (size_t)row * S;
    unsigned short* pr      = probs  + (size_t)row * S;
    const int tid  = threadIdx.x;
    const int lane = tid & 63;
    const int wav  = tid >> 6;

    uint4 raw = *(const uint4*)(p + tid * 8);   // 8 bf16
    float v[8];
    v[0] = __uint_as_float(raw.x << 16); v[1] = __uint_as_float(raw.x & 0xffff0000u);
    v[2] = __uint_as_float(raw.y << 16); v[3] = __uint_as_float(raw.y & 0xffff0000u);
    v[4] = __uint_as_float(raw.z << 16); v[5] = __uint_as_float(raw.z & 0xffff0000u);
    v[6] = __uint_as_float(raw.w << 16); v[7] = __uint_as_float(raw.w & 0xffff0000u);

    float mx = v[0];
#pragma unroll
    for (int k = 1; k < 8; k++) mx = fmaxf(mx, v[k]);
#pragma unroll
    for (int off = 32; off > 0; off >>= 1) mx = fmaxf(mx, __shfl_down(mx, off));
    if (lane == 0) red[wav] = mx;
    __syncthreads();
    mx = fmaxf(fmaxf(red[0], red[1]), fmaxf(red[2], red[3]));
    __syncthreads();

    float s = 0.f;
#pragma unroll
    for (int k = 0; k < 8; k++) { v[k] = __expf(v[k] - mx); s += v[k]; }
#pragma unroll
    for (int off = 32; off > 0; off >>= 1) s += __shfl_down(s, off);
    if (lane == 0) red[wav] = s;
    __syncthreads();
    s = red[0] + red[1] + red[2] + red[3];
    float inv = 1.0f / s;

    uint4 o;
    o.x = (unsigned)f2bf(v[0] * inv) | ((unsigned)f2bf(v[1] * inv) << 16);
    o.y = (unsigned)f2bf(v[2] * inv) | ((unsigned)f2bf(v[3] * inv) << 16);
    o.z = (unsigned)f2bf(v[4] * inv) | ((unsigned)f2bf(v[5] * inv) << 16);
    o.w = (unsigned)f2bf(v[6] * inv) | ((unsigned)f2bf(v[7] * inv) << 16);
    *(uint4*)(pr + tid * 8) = o;
}

// ---------------------------------------------------------------------------
// out_row = LayerNorm(X_row)*g + b.  D = 1024. In-place safe (out == X).
// ---------------------------------------------------------------------------
template<int WRITE_BF16>
__global__ __launch_bounds__(256) void ln_kernel(
    const float* __restrict__ X,
    const float* __restrict__ g, const float* __restrict__ bta,
    float* __restrict__ out, unsigned short* __restrict__ out16, int D)
{
    __shared__ float red[8];
    const int row = blockIdx.x;
    const float* x = X + (size_t)row * D;
    const int tid  = threadIdx.x;
    const int lane = tid & 63;
    const int wav  = tid >> 6;

    float4 a = *(const float4*)(x + tid * 4);
    float v0 = a.x, v1 = a.y, v2 = a.z, v3 = a.w;

    float s1 = v0 + v1 + v2 + v3;
    float s2 = v0 * v0 + v1 * v1 + v2 * v2 + v3 * v3;
#pragma unroll
    for (int off = 32; off > 0; off >>= 1) {
        s1 += __shfl_down(s1, off);
        s2 += __shfl_down(s2, off);
    }
    if (lane == 0) { red[wav] = s1; red[4 + wav] = s2; }
    __syncthreads();
    s1 = red[0] + red[1] + red[2] + red[3];
    s2 = red[4] + red[5] + red[6] + red[7];
    const float mu  = s1 / (float)D;
    const float var = s2 / (float)D - mu * mu;
    const float rs  = rsqrtf(var + LN_EPS);

    float4 gg = *(const float4*)(g + tid * 4);
    float4 bb = *(const float4*)(bta + tid * 4);
    float4 r;
    r.x = (v0 - mu) * rs * gg.x + bb.x;
    r.y = (v1 - mu) * rs * gg.y + bb.y;
    r.z = (v2 - mu) * rs * gg.z + bb.z;
    r.w = (v3 - mu) * rs * gg.w + bb.w;
    *(float4*)(out + (size_t)row * D + tid * 4) = r;
    if (WRITE_BF16) {
        ushort4 h;
        h.x = f2bf(r.x); h.y = f2bf(r.y); h.z = f2bf(r.z); h.w = f2bf(r.w);
        *(ushort4*)(out16 + (size_t)row * D + tid * 4) = h;
    }
}

// ---------------------------------------------------------------------------
extern "C" void kernel_launch(void* const* d_in, const int* in_sizes, int n_in,
                              void* d_out, int out_size, void* d_ws, size_t ws_size,
                              hipStream_t stream) {
    (void)in_sizes; (void)n_in; (void)out_size; (void)ws_size;
    const float* x    = (const float*)d_in[0];
    const float* mask = (const float*)d_in[1];
    const float* w1   = (const float*)d_in[2];
    const float* b1   = (const float*)d_in[3];
    const float* w2   = (const float*)d_in[4];
    const float* b2   = (const float*)d_in[5];
    const float* ln1g = (const float*)d_in[6];
    const float* ln1b = (const float*)d_in[7];
    const float* ln2g = (const float*)d_in[8];
    const float* ln2b = (const float*)d_in[9];
    float* out = (float*)d_out;

    const int B = 4, S = 2048, D = 1024, DFF = 4096;
    const size_t MB = 1024 * 1024;

    // ws (128 MiB):
    //  [0,32M):   scoresb bf16 (1-2)         } act bf16 [0,64M) (5-6)
    //  [32,64M):  xb bf16 [32,48M) (prep-1), then probs bf16 (2-3)
    //  [64,96M):  hbuf fp32 = h (3-6)
    //  [96,112M): hb16 bf16 (4-5)
    //  [112,120M): w1T   [120,128M): w2T
    // d_out (32 MiB): xTb [0,16M) (prep-3); then fsum fp32 = h+ffn (6-7), LN in place.
    char* ws = (char*)d_ws;
    unsigned short* scoresb = (unsigned short*)ws;
    unsigned short* act     = (unsigned short*)ws;
    unsigned short* xb      = (unsigned short*)(ws + 32 * MB);
    unsigned short* probs   = (unsigned short*)(ws + 32 * MB);
    float*          hbuf    = (float*)(ws + 64 * MB);
    unsigned short* hb16    = (unsigned short*)(ws + 96 * MB);
    unsigned short* w1T     = (unsigned short*)(ws + 112 * MB);
    unsigned short* w2T     = (unsigned short*)(ws + 120 * MB);
    unsigned short* xTb     = (unsigned short*)d_out;
    float*          fsum    = (float*)d_out;

    // --- prep ---
    x_prep_kernel<<<dim3(D / 32, S / 32, B), 256, 0, stream>>>(
        x, xb, xTb, S, D, (long)S * D);
    transpose_cvt_kernel<<<dim3(DFF / 32, D / 32, 1), 256, 0, stream>>>(w1, w1T, D, DFF);
    transpose_cvt_kernel<<<dim3(D / 32, DFF / 32, 1), 256, 0, stream>>>(w2, w2T, DFF, D);

    // 1. scoresb[b] = (xb[b] @ xb[b]^T)*scale + mask  -> bf16
    hipLaunchKernelGGL((gemm_bt<3>), dim3(S / 128, S / 128, B), dim3(256), 0, stream,
                       xb, xb, mask, (const float*)nullptr, (void*)scoresb,
                       S, S, D, (long)S * D, (long)S * D, (long)S * S, (long)S, 0.03125f);
    // 2. probs = softmax(scoresb) -> bf16
    softmax_bf16_kernel<<<B * S, 256, 0, stream>>>(scoresb, probs, S);
    // 3. hbuf[b] = x[b] + probs[b] @ xTb[b]^T  -> fp32
    hipLaunchKernelGGL((gemm_bt<4>), dim3(D / 128, S / 128, B), dim3(256), 0, stream,
                       probs, xTb, (const float*)nullptr, x, (void*)hbuf,
                       S, D, S, (long)S * S, (long)D * S, (long)S * D, 0L, 0.f);
    // 4. h = LN(hbuf) in place + hb16 bf16
    hipLaunchKernelGGL((ln_kernel<1>), dim3(B * S), dim3(256), 0, stream,
                       hbuf, ln1g, ln1b, hbuf, hb16, D);
    // 5. act = gelu(h @ w1 + b1) -> bf16
    hipLaunchKernelGGL((gemm_bt<2>), dim3(DFF / 128, (B * S) / 128, 1), dim3(256), 0, stream,
                       hb16, w1T, b1, (const float*)nullptr, (void*)act,
                       B * S, DFF, D, 0L, 0L, 0L, 0L, 0.f);
    // 6. fsum = h + act @ w2 + b2 -> fp32 (into d_out)
    hipLaunchKernelGGL((gemm_bt<5>), dim3(D / 128, (B * S) / 128, 1), dim3(256), 0, stream,
                       act, w2T, b2, hbuf, (void*)fsum,
                       B * S, D, DFF, 0L, 0L, 0L, 0L, 0.f);
    // 7. out = LN(fsum) in place
    hipLaunchKernelGGL((ln_kernel<0>), dim3(B * S), dim3(256), 0, stream,
                       fsum, ln2g, ln2b, out, (unsigned short*)nullptr, D);
}

// Round 6
// 634.546 us; speedup vs baseline: 1.0482x; 1.0482x over previous
//
#include <hip/hip_runtime.h>
#include <hip/hip_bf16.h>
#include <math.h>

#define LN_EPS 1e-5f

typedef short short8 __attribute__((ext_vector_type(8)));
typedef float floatx4 __attribute__((ext_vector_type(4)));

__device__ inline unsigned short f2bf(float f) {
    unsigned int u = __float_as_uint(f);
    u += 0x7fff + ((u >> 16) & 1);   // round-to-nearest-even
    return (unsigned short)(u >> 16);
}

__device__ inline void gl_lds16(const unsigned short* g, unsigned short* l) {
    __builtin_amdgcn_global_load_lds(
        (__attribute__((address_space(1))) const void*)g,
        (__attribute__((address_space(3))) void*)l, 16, 0, 0);
}

// overflow-safe tanh-approx GELU (max abs err ~1e-3 vs exact)
__device__ inline float gelu_f(float v) {
    float u2 = 2.0f * v * (0.7978845608f + 0.0356774081f * v * v);
    float t  = 1.0f - 2.0f / (__expf(u2) + 1.0f);
    return 0.5f * v * (1.0f + t);
}

// ---------------------------------------------------------------------------
// bf16 MFMA GEMM, 256x128 block tile, 4 waves, WAVE TILE 128x64 (acc 8x4).
// Register blocking: per-wave LDS reads 24 KB/iter for 4.2 MFLOP/block-iter
// (vs 64x64 tile: 16 KB for 2.1) -> LDS-read cycles ~ MFMA cycles.
//  A: MxK row-major bf16 (staged to LDS, global_load_lds w=16)
//  B: NxK row-major bf16 (B^T given; staged to LDS -> 16x cross-block reuse)
// Swapped-operand MFMA: mfma(bfr, afr) -> lane holds 4 consecutive out cols.
//  EPI: 2 = +bias, GELU, bf16 out
//       3 = *scale + mask[batch][col], bf16 out       (QK^T scores)
//       4 = +resid[batch], fp32 out                   (PV: x + attn)
//       5 = +bias +resid, fp32 out                    (FFN2: h + ffn)
// M mult of 256; N mult of 128; K mult of 64.
// ---------------------------------------------------------------------------
template<int EPI>
__global__ __launch_bounds__(256) void gemm_bt(
    const unsigned short* __restrict__ A, const unsigned short* __restrict__ B,
    const float* __restrict__ bias, const float* __restrict__ resid,
    void* __restrict__ Cptr,
    int M, int N, int K, long sA, long sB, long sC, long sBias, float scale)
{
    __shared__ unsigned short lds_a[2][256 * 32];   // two k-halves, [m][k]
    __shared__ unsigned short lds_b[2][128 * 32];   // two k-halves, [n][k]

    const int tid  = threadIdx.x;
    const int lane = tid & 63;
    const int wave = tid >> 6;
    const int quad = lane >> 4;
    const int l16  = lane & 15;
    const int wm = wave >> 1, wn = wave & 1;
    const int tile_m = blockIdx.y * 256;
    const int tile_n = blockIdx.x * 128;
    const int batch  = blockIdx.z;

    const unsigned short* Ab = A + (size_t)batch * sA;
    const unsigned short* Bb = B + (size_t)batch * sB;

    // staging: call r covers rows r*64 + wave*16 + (lane>>2), 16B at (lane&3)*8
    const int srow = wave * 16 + (lane >> 2);
    const int scol = (lane & 3) * 8;
    const unsigned short* gA[4];
#pragma unroll
    for (int r = 0; r < 4; r++)
        gA[r] = Ab + (size_t)(tile_m + r * 64 + srow) * K + scol;
    const unsigned short* gB[2];
#pragma unroll
    for (int r = 0; r < 2; r++)
        gB[r] = Bb + (size_t)(tile_n + r * 64 + srow) * K + scol;
    // LDS dest: wave-uniform base + lane*16B (row-major [m][32] works out)
    unsigned short* lA[4];
#pragma unroll
    for (int r = 0; r < 4; r++) lA[r] = &lds_a[0][(r * 64 + wave * 16) * 32 + lane * 8];
    unsigned short* lB[2];
#pragma unroll
    for (int r = 0; r < 2; r++) lB[r] = &lds_b[0][(r * 64 + wave * 16) * 32 + lane * 8];
    const int halfstep_a = 256 * 32;   // shorts between lds_a halves
    const int halfstep_b = 128 * 32;

    floatx4 acc[8][4];
    const floatx4 zero = {0.f, 0.f, 0.f, 0.f};
#pragma unroll
    for (int i = 0; i < 8; i++)
#pragma unroll
        for (int j = 0; j < 4; j++) acc[i][j] = zero;

    for (int k0 = 0; k0 < K; k0 += 64) {
        __syncthreads();   // all waves done reading LDS from previous iter
#pragma unroll
        for (int r = 0; r < 4; r++) gl_lds16(gA[r] + k0, lA[r]);
#pragma unroll
        for (int r = 0; r < 2; r++) gl_lds16(gB[r] + k0, lB[r]);
#pragma unroll
        for (int r = 0; r < 4; r++) gl_lds16(gA[r] + k0 + 32, lA[r] + halfstep_a);
#pragma unroll
        for (int r = 0; r < 2; r++) gl_lds16(gB[r] + k0 + 32, lB[r] + halfstep_b);
        __syncthreads();   // drain staging

#pragma unroll
        for (int h = 0; h < 2; h++) {
            short8 bfr[4];
#pragma unroll
            for (int j = 0; j < 4; j++)
                bfr[j] = *(const short8*)
                    &lds_b[h][(wn * 64 + j * 16 + l16) * 32 + quad * 8];
#pragma unroll
            for (int i = 0; i < 8; i++) {
                short8 afr = *(const short8*)
                    &lds_a[h][(wm * 128 + i * 16 + l16) * 32 + quad * 8];
#pragma unroll
                for (int j = 0; j < 4; j++)
                    acc[i][j] = __builtin_amdgcn_mfma_f32_16x16x32_bf16(
                        bfr[j], afr, acc[i][j], 0, 0, 0);
            }
        }
    }

    // ---- epilogue: per frag, lane holds row (l16) x 4 consecutive cols ----
#pragma unroll
    for (int i = 0; i < 8; i++) {
        const int row = tile_m + wm * 128 + i * 16 + l16;
#pragma unroll
        for (int j = 0; j < 4; j++) {
            const int colb = tile_n + wn * 64 + j * 16 + quad * 4;
            float v[4];
#pragma unroll
            for (int r = 0; r < 4; r++) v[r] = acc[i][j][r];

            if (EPI == 3) {
                float4 mv = *(const float4*)&bias[(size_t)batch * sBias + colb];
                v[0] = v[0] * scale + mv.x;  v[1] = v[1] * scale + mv.y;
                v[2] = v[2] * scale + mv.z;  v[3] = v[3] * scale + mv.w;
            }
            if (EPI == 2 || EPI == 5) {
                float4 bv = *(const float4*)&bias[colb];
                v[0] += bv.x; v[1] += bv.y; v[2] += bv.z; v[3] += bv.w;
            }
            if (EPI == 2) {
#pragma unroll
                for (int r = 0; r < 4; r++) v[r] = gelu_f(v[r]);
            }
            if (EPI == 4 || EPI == 5) {
                float4 rv = *(const float4*)&resid[(size_t)batch * sC +
                                                   (size_t)row * N + colb];
                v[0] += rv.x; v[1] += rv.y; v[2] += rv.z; v[3] += rv.w;
            }

            if (EPI == 2 || EPI == 3) {
                unsigned short* C = (unsigned short*)Cptr + (size_t)batch * sC;
                ushort4 h4;
                h4.x = f2bf(v[0]); h4.y = f2bf(v[1]);
                h4.z = f2bf(v[2]); h4.w = f2bf(v[3]);
                *(ushort4*)(C + (size_t)row * N + colb) = h4;
            } else {
                float* C = (float*)Cptr + (size_t)batch * sC;
                float4 f4 = {v[0], v[1], v[2], v[3]};
                *(float4*)(C + (size_t)row * N + colb) = f4;
            }
        }
    }
}

// ---------------------------------------------------------------------------
// x prep: read x [S,D] fp32 once -> xb [S,D] bf16 AND xTb [D,S] bf16.
// ---------------------------------------------------------------------------
__global__ __launch_bounds__(256) void x_prep_kernel(
    const float* __restrict__ in, unsigned short* __restrict__ straight,
    unsigned short* __restrict__ transposed, int R, int C, long sIn)
{
    __shared__ float tile[32][33];
    const int tc = blockIdx.x * 32, tr = blockIdx.y * 32;
    const float* src = in + (size_t)blockIdx.z * sIn;
    unsigned short* dstS = straight   + (size_t)blockIdx.z * sIn;
    unsigned short* dstT = transposed + (size_t)blockIdx.z * sIn;
    const int tx = threadIdx.x & 31, ty = threadIdx.x >> 5;
#pragma unroll
    for (int i = 0; i < 4; i++) {
        float val = src[(size_t)(tr + ty + i * 8) * C + tc + tx];
        tile[ty + i * 8][tx] = val;
        dstS[(size_t)(tr + ty + i * 8) * C + tc + tx] = f2bf(val);
    }
    __syncthreads();
#pragma unroll
    for (int i = 0; i < 4; i++)
        dstT[(size_t)(tc + ty + i * 8) * R + tr + tx] = f2bf(tile[tx][ty + i * 8]);
}

// ---------------------------------------------------------------------------
__global__ __launch_bounds__(256) void transpose_cvt_kernel(
    const float* __restrict__ in, unsigned short* __restrict__ out, int R, int C)
{
    __shared__ float tile[32][33];
    const int tc = blockIdx.x * 32, tr = blockIdx.y * 32;
    const int tx = threadIdx.x & 31, ty = threadIdx.x >> 5;
#pragma unroll
    for (int i = 0; i < 4; i++)
        tile[ty + i * 8][tx] = in[(size_t)(tr + ty + i * 8) * C + tc + tx];
    __syncthreads();
#pragma unroll
    for (int i = 0; i < 4; i++)
        out[(size_t)(tc + ty + i * 8) * R + tr + tx] = f2bf(tile[tx][ty + i * 8]);
}

// ---------------------------------------------------------------------------
// Pure row softmax over S=2048: bf16 in (scale+mask pre-applied) -> bf16 out.
// ---------------------------------------------------------------------------
__global__ __launch_bounds__(256) void softmax_bf16_kernel(
    const unsigned short* __restrict__ scores, unsigned short* __restrict__ probs,
    int S)
{
    __shared__ float red[4];
    const int row = blockIdx.x;
    const unsigned short* p = scores + (size_t)row * S;
    unsigned short* pr      = probs  + (size_t)row * S;
    const int tid  = threadIdx.x;
    const int lane = tid & 63;
    const int wav  = tid >> 6;

    uint4 raw = *(const uint4*)(p + tid * 8);   // 8 bf16
    float v[8];
    v[0] = __uint_as_float(raw.x << 16); v[1] = __uint_as_float(raw.x & 0xffff0000u);
    v[2] = __uint_as_float(raw.y << 16); v[3] = __uint_as_float(raw.y & 0xffff0000u);
    v[4] = __uint_as_float(raw.z << 16); v[5] = __uint_as_float(raw.z & 0xffff0000u);
    v[6] = __uint_as_float(raw.w << 16); v[7] = __uint_as_float(raw.w & 0xffff0000u);

    float mx = v[0];
#pragma unroll
    for (int k = 1; k < 8; k++) mx = fmaxf(mx, v[k]);
#pragma unroll
    for (int off = 32; off > 0; off >>= 1) mx = fmaxf(mx, __shfl_down(mx, off));
    if (lane == 0) red[wav] = mx;
    __syncthreads();
    mx = fmaxf(fmaxf(red[0], red[1]), fmaxf(red[2], red[3]));
    __syncthreads();

    float s = 0.f;
#pragma unroll
    for (int k = 0; k < 8; k++) { v[k] = __expf(v[k] - mx); s += v[k]; }
#pragma unroll
    for (int off = 32; off > 0; off >>= 1) s += __shfl_down(s, off);
    if (lane == 0) red[wav] = s;
    __syncthreads();
    s = red[0] + red[1] + red[2] + red[3];
    float inv = 1.0f / s;

    uint4 o;
    o.x = (unsigned)f2bf(v[0] * inv) | ((unsigned)f2bf(v[1] * inv) << 16);
    o.y = (unsigned)f2bf(v[2] * inv) | ((unsigned)f2bf(v[3] * inv) << 16);
    o.z = (unsigned)f2bf(v[4] * inv) | ((unsigned)f2bf(v[5] * inv) << 16);
    o.w = (unsigned)f2bf(v[6] * inv) | ((unsigned)f2bf(v[7] * inv) << 16);
    *(uint4*)(pr + tid * 8) = o;
}

// ---------------------------------------------------------------------------
// out_row = LayerNorm(X_row)*g + b.  D = 1024. In-place safe (out == X).
// ---------------------------------------------------------------------------
template<int WRITE_BF16>
__global__ __launch_bounds__(256) void ln_kernel(
    const float* __restrict__ X,
    const float* __restrict__ g, const float* __restrict__ bta,
    float* __restrict__ out, unsigned short* __restrict__ out16, int D)
{
    __shared__ float red[8];
    const int row = blockIdx.x;
    const float* x = X + (size_t)row * D;
    const int tid  = threadIdx.x;
    const int lane = tid & 63;
    const int wav  = tid >> 6;

    float4 a = *(const float4*)(x + tid * 4);
    float v0 = a.x, v1 = a.y, v2 = a.z, v3 = a.w;

    float s1 = v0 + v1 + v2 + v3;
    float s2 = v0 * v0 + v1 * v1 + v2 * v2 + v3 * v3;
#pragma unroll
    for (int off = 32; off > 0; off >>= 1) {
        s1 += __shfl_down(s1, off);
        s2 += __shfl_down(s2, off);
    }
    if (lane == 0) { red[wav] = s1; red[4 + wav] = s2; }
    __syncthreads();
    s1 = red[0] + red[1] + red[2] + red[3];
    s2 = red[4] + red[5] + red[6] + red[7];
    const float mu  = s1 / (float)D;
    const float var = s2 / (float)D - mu * mu;
    const float rs  = rsqrtf(var + LN_EPS);

    float4 gg = *(const float4*)(g + tid * 4);
    float4 bb = *(const float4*)(bta + tid * 4);
    float4 r;
    r.x = (v0 - mu) * rs * gg.x + bb.x;
    r.y = (v1 - mu) * rs * gg.y + bb.y;
    r.z = (v2 - mu) * rs * gg.z + bb.z;
    r.w = (v3 - mu) * rs * gg.w + bb.w;
    *(float4*)(out + (size_t)row * D + tid * 4) = r;
    if (WRITE_BF16) {
        ushort4 h;
        h.x = f2bf(r.x); h.y = f2bf(r.y); h.z = f2bf(r.z); h.w = f2bf(r.w);
        *(ushort4*)(out16 + (size_t)row * D + tid * 4) = h;
    }
}

// ---------------------------------------------------------------------------
extern "C" void kernel_launch(void* const* d_in, const int* in_sizes, int n_in,
                              void* d_out, int out_size, void* d_ws, size_t ws_size,
                              hipStream_t stream) {
    (void)in_sizes; (void)n_in; (void)out_size; (void)ws_size;
    const float* x    = (const float*)d_in[0];
    const float* mask = (const float*)d_in[1];
    const float* w1   = (const float*)d_in[2];
    const float* b1   = (const float*)d_in[3];
    const float* w2   = (const float*)d_in[4];
    const float* b2   = (const float*)d_in[5];
    const float* ln1g = (const float*)d_in[6];
    const float* ln1b = (const float*)d_in[7];
    const float* ln2g = (const float*)d_in[8];
    const float* ln2b = (const float*)d_in[9];
    float* out = (float*)d_out;

    const int B = 4, S = 2048, D = 1024, DFF = 4096;
    const size_t MB = 1024 * 1024;

    // ws (128 MiB):
    //  [0,32M):   scoresb bf16 (1-2)         } act bf16 [0,64M) (5-6)
    //  [32,64M):  xb bf16 [32,48M) (prep-1), then probs bf16 (2-3)
    //  [64,96M):  hbuf fp32 = h (3-6)
    //  [96,112M): hb16 bf16 (4-5)
    //  [112,120M): w1T   [120,128M): w2T
    // d_out (32 MiB): xTb [0,16M) (prep-3); then fsum fp32 = h+ffn (6-7), LN in place.
    char* ws = (char*)d_ws;
    unsigned short* scoresb = (unsigned short*)ws;
    unsigned short* act     = (unsigned short*)ws;
    unsigned short* xb      = (unsigned short*)(ws + 32 * MB);
    unsigned short* probs   = (unsigned short*)(ws + 32 * MB);
    float*          hbuf    = (float*)(ws + 64 * MB);
    unsigned short* hb16    = (unsigned short*)(ws + 96 * MB);
    unsigned short* w1T     = (unsigned short*)(ws + 112 * MB);
    unsigned short* w2T     = (unsigned short*)(ws + 120 * MB);
    unsigned short* xTb     = (unsigned short*)d_out;
    float*          fsum    = (float*)d_out;

    // --- prep ---
    x_prep_kernel<<<dim3(D / 32, S / 32, B), 256, 0, stream>>>(
        x, xb, xTb, S, D, (long)S * D);
    transpose_cvt_kernel<<<dim3(DFF / 32, D / 32, 1), 256, 0, stream>>>(w1, w1T, D, DFF);
    transpose_cvt_kernel<<<dim3(D / 32, DFF / 32, 1), 256, 0, stream>>>(w2, w2T, DFF, D);

    // 1. scoresb[b] = (xb[b] @ xb[b]^T)*scale + mask  -> bf16
    hipLaunchKernelGGL((gemm_bt<3>), dim3(S / 128, S / 256, B), dim3(256), 0, stream,
                       xb, xb, mask, (const float*)nullptr, (void*)scoresb,
                       S, S, D, (long)S * D, (long)S * D, (long)S * S, (long)S, 0.03125f);
    // 2. probs = softmax(scoresb) -> bf16
    softmax_bf16_kernel<<<B * S, 256, 0, stream>>>(scoresb, probs, S);
    // 3. hbuf[b] = x[b] + probs[b] @ xTb[b]^T  -> fp32
    hipLaunchKernelGGL((gemm_bt<4>), dim3(D / 128, S / 256, B), dim3(256), 0, stream,
                       probs, xTb, (const float*)nullptr, x, (void*)hbuf,
                       S, D, S, (long)S * S, (long)D * S, (long)S * D, 0L, 0.f);
    // 4. h = LN(hbuf) in place + hb16 bf16
    hipLaunchKernelGGL((ln_kernel<1>), dim3(B * S), dim3(256), 0, stream,
                       hbuf, ln1g, ln1b, hbuf, hb16, D);
    // 5. act = gelu(h @ w1 + b1) -> bf16
    hipLaunchKernelGGL((gemm_bt<2>), dim3(DFF / 128, (B * S) / 256, 1), dim3(256), 0, stream,
                       hb16, w1T, b1, (const float*)nullptr, (void*)act,
                       B * S, DFF, D, 0L, 0L, 0L, 0L, 0.f);
    // 6. fsum = h + act @ w2 + b2 -> fp32 (into d_out)
    hipLaunchKernelGGL((gemm_bt<5>), dim3(D / 128, (B * S) / 256, 1), dim3(256), 0, stream,
                       act, w2T, b2, hbuf, (void*)fsum,
                       B * S, D, DFF, 0L, 0L, 0L, 0L, 0.f);
    // 7. out = LN(fsum) in place
    hipLaunchKernelGGL((ln_kernel<0>), dim3(B * S), dim3(256), 0, stream,
                       fsum, ln2g, ln2b, out, (unsigned short*)nullptr, D);
}

// Round 7
// 454.681 us; speedup vs baseline: 1.4628x; 1.3956x over previous
//
#include <hip/hip_runtime.h>
#include <hip/hip_bf16.h>
#include <math.h>

#define LN_EPS 1e-5f

typedef short short8 __attribute__((ext_vector_type(8)));
typedef float floatx4 __attribute__((ext_vector_type(4)));

__device__ inline unsigned short f2bf(float f) {
    unsigned int u = __float_as_uint(f);
    u += 0x7fff + ((u >> 16) & 1);   // round-to-nearest-even
    return (unsigned short)(u >> 16);
}

__device__ inline void gl_lds16(const unsigned short* g, unsigned short* l) {
    __builtin_amdgcn_global_load_lds(
        (__attribute__((address_space(1))) const void*)g,
        (__attribute__((address_space(3))) void*)l, 16, 0, 0);
}

// overflow-safe tanh-approx GELU (max abs err ~1e-3 vs exact)
__device__ inline float gelu_f(float v) {
    float u2 = 2.0f * v * (0.7978845608f + 0.0356774081f * v * v);
    float t  = 1.0f - 2.0f / (__expf(u2) + 1.0f);
    return 0.5f * v * (1.0f + t);
}

// ---------------------------------------------------------------------------
// bf16 MFMA GEMM, 128x128 block tile, 64x64 wave tiles, BK=64,
// EXPLICIT DOUBLE-BUFFERED LDS (one barrier/iter; stage k+64 issued async
// BEFORE compute of k -> global-load latency hidden under ~1000 cyc of
// LDS reads + MFMA instead of being drained cold at a second barrier).
//  A: MxK row-major bf16.  B: NxK row-major bf16 (B^T given). Both in LDS
//  (direct-to-VGPR B was round-5's 2x regression: kills 16x L2 reuse).
// Swapped-operand MFMA: mfma(bfr, afr) -> lane holds 4 consecutive out cols.
//  EPI: 2 = +bias, GELU, bf16 out
//       3 = *scale + mask[batch][col], bf16 out       (QK^T scores)
//       4 = +resid[batch], fp32 out                   (PV: x + attn)
//       5 = +bias +resid, fp32 out                    (FFN2: h + ffn)
// M,N mult of 128; K mult of 128 (>=2 iters for the dbuf prologue).
// ---------------------------------------------------------------------------
template<int EPI>
__global__ __launch_bounds__(256) void gemm_bt(
    const unsigned short* __restrict__ A, const unsigned short* __restrict__ B,
    const float* __restrict__ bias, const float* __restrict__ resid,
    void* __restrict__ Cptr,
    int M, int N, int K, long sA, long sB, long sC, long sBias, float scale)
{
    // [buf][half][m*32+k] ; half = k-halves of the 64-wide K tile
    __shared__ unsigned short lds_a[2][2][128 * 32];   // 32 KB
    __shared__ unsigned short lds_b[2][2][128 * 32];   // 32 KB

    const int tid  = threadIdx.x;
    const int lane = tid & 63;
    const int wave = tid >> 6;
    const int quad = lane >> 4;
    const int l16  = lane & 15;
    const int wm = wave >> 1, wn = wave & 1;
    const int tile_m = blockIdx.y * 128;
    const int tile_n = blockIdx.x * 128;
    const int batch  = blockIdx.z;

    const unsigned short* Ab = A + (size_t)batch * sA;
    const unsigned short* Bb = B + (size_t)batch * sB;

    // staging: each wave covers rows {wave*16..+16} of each 64-row block,
    // 16B per lane at k-offset (lane&3)*8; LDS dest = wave-uniform + lane*16B.
    const int srow = wave * 16 + (lane >> 2);
    const int scol = (lane & 3) * 8;
    const unsigned short* gA0 = Ab + (size_t)(tile_m + srow) * K + scol;
    const unsigned short* gA1 = Ab + (size_t)(tile_m + 64 + srow) * K + scol;
    const unsigned short* gB0 = Bb + (size_t)(tile_n + srow) * K + scol;
    const unsigned short* gB1 = Bb + (size_t)(tile_n + 64 + srow) * K + scol;
    const int off = wave * 512 + lane * 8;   // within one [128*32] half

    floatx4 acc[4][4];
    const floatx4 zero = {0.f, 0.f, 0.f, 0.f};
#pragma unroll
    for (int i = 0; i < 4; i++)
#pragma unroll
        for (int j = 0; j < 4; j++) acc[i][j] = zero;

    auto stage = [&](int buf, int k0) {
        gl_lds16(gA0 + k0,      &lds_a[buf][0][off]);
        gl_lds16(gA1 + k0,      &lds_a[buf][0][2048 + off]);
        gl_lds16(gB0 + k0,      &lds_b[buf][0][off]);
        gl_lds16(gB1 + k0,      &lds_b[buf][0][2048 + off]);
        gl_lds16(gA0 + k0 + 32, &lds_a[buf][1][off]);
        gl_lds16(gA1 + k0 + 32, &lds_a[buf][1][2048 + off]);
        gl_lds16(gB0 + k0 + 32, &lds_b[buf][1][off]);
        gl_lds16(gB1 + k0 + 32, &lds_b[buf][1][2048 + off]);
    };

    stage(0, 0);
    int cur = 0;
    for (int k0 = 0; k0 < K; k0 += 64) {
        // drain own outstanding stage (vmcnt0) + all waves past prev reads
        __syncthreads();
        if (k0 + 64 < K) stage(1 ^ cur, k0 + 64);   // async; drained NEXT iter

#pragma unroll
        for (int h = 0; h < 2; h++) {
            short8 afr[4], bfr[4];
#pragma unroll
            for (int i = 0; i < 4; i++)
                afr[i] = *(const short8*)
                    &lds_a[cur][h][(wm * 64 + i * 16 + l16) * 32 + quad * 8];
#pragma unroll
            for (int j = 0; j < 4; j++)
                bfr[j] = *(const short8*)
                    &lds_b[cur][h][(wn * 64 + j * 16 + l16) * 32 + quad * 8];
#pragma unroll
            for (int i = 0; i < 4; i++)
#pragma unroll
                for (int j = 0; j < 4; j++)
                    acc[i][j] = __builtin_amdgcn_mfma_f32_16x16x32_bf16(
                        bfr[j], afr[i], acc[i][j], 0, 0, 0);
        }
        cur ^= 1;
    }

    // ---- epilogue: per frag, lane holds row (l16) x 4 consecutive cols ----
#pragma unroll
    for (int i = 0; i < 4; i++) {
        const int row = tile_m + wm * 64 + i * 16 + l16;
#pragma unroll
        for (int j = 0; j < 4; j++) {
            const int colb = tile_n + wn * 64 + j * 16 + quad * 4;
            float v[4];
#pragma unroll
            for (int r = 0; r < 4; r++) v[r] = acc[i][j][r];

            if (EPI == 3) {
                float4 mv = *(const float4*)&bias[(size_t)batch * sBias + colb];
                v[0] = v[0] * scale + mv.x;  v[1] = v[1] * scale + mv.y;
                v[2] = v[2] * scale + mv.z;  v[3] = v[3] * scale + mv.w;
            }
            if (EPI == 2 || EPI == 5) {
                float4 bv = *(const float4*)&bias[colb];
                v[0] += bv.x; v[1] += bv.y; v[2] += bv.z; v[3] += bv.w;
            }
            if (EPI == 2) {
#pragma unroll
                for (int r = 0; r < 4; r++) v[r] = gelu_f(v[r]);
            }
            if (EPI == 4 || EPI == 5) {
                float4 rv = *(const float4*)&resid[(size_t)batch * sC +
                                                   (size_t)row * N + colb];
                v[0] += rv.x; v[1] += rv.y; v[2] += rv.z; v[3] += rv.w;
            }

            if (EPI == 2 || EPI == 3) {
                unsigned short* C = (unsigned short*)Cptr + (size_t)batch * sC;
                ushort4 h4;
                h4.x = f2bf(v[0]); h4.y = f2bf(v[1]);
                h4.z = f2bf(v[2]); h4.w = f2bf(v[3]);
                *(ushort4*)(C + (size_t)row * N + colb) = h4;
            } else {
                float* C = (float*)Cptr + (size_t)batch * sC;
                float4 f4 = {v[0], v[1], v[2], v[3]};
                *(float4*)(C + (size_t)row * N + colb) = f4;
            }
        }
    }
}

// ---------------------------------------------------------------------------
// x prep: read x [S,D] fp32 once -> xb [S,D] bf16 AND xTb [D,S] bf16.
// ---------------------------------------------------------------------------
__global__ __launch_bounds__(256) void x_prep_kernel(
    const float* __restrict__ in, unsigned short* __restrict__ straight,
    unsigned short* __restrict__ transposed, int R, int C, long sIn)
{
    __shared__ float tile[32][33];
    const int tc = blockIdx.x * 32, tr = blockIdx.y * 32;
    const float* src = in + (size_t)blockIdx.z * sIn;
    unsigned short* dstS = straight   + (size_t)blockIdx.z * sIn;
    unsigned short* dstT = transposed + (size_t)blockIdx.z * sIn;
    const int tx = threadIdx.x & 31, ty = threadIdx.x >> 5;
#pragma unroll
    for (int i = 0; i < 4; i++) {
        float val = src[(size_t)(tr + ty + i * 8) * C + tc + tx];
        tile[ty + i * 8][tx] = val;
        dstS[(size_t)(tr + ty + i * 8) * C + tc + tx] = f2bf(val);
    }
    __syncthreads();
#pragma unroll
    for (int i = 0; i < 4; i++)
        dstT[(size_t)(tc + ty + i * 8) * R + tr + tx] = f2bf(tile[tx][ty + i * 8]);
}

// ---------------------------------------------------------------------------
__global__ __launch_bounds__(256) void transpose_cvt_kernel(
    const float* __restrict__ in, unsigned short* __restrict__ out, int R, int C)
{
    __shared__ float tile[32][33];
    const int tc = blockIdx.x * 32, tr = blockIdx.y * 32;
    const int tx = threadIdx.x & 31, ty = threadIdx.x >> 5;
#pragma unroll
    for (int i = 0; i < 4; i++)
        tile[ty + i * 8][tx] = in[(size_t)(tr + ty + i * 8) * C + tc + tx];
    __syncthreads();
#pragma unroll
    for (int i = 0; i < 4; i++)
        out[(size_t)(tc + ty + i * 8) * R + tr + tx] = f2bf(tile[tx][ty + i * 8]);
}

// ---------------------------------------------------------------------------
// Pure row softmax over S=2048: bf16 in (scale+mask pre-applied) -> bf16 out.
// ---------------------------------------------------------------------------
__global__ __launch_bounds__(256) void softmax_bf16_kernel(
    const unsigned short* __restrict__ scores, unsigned short* __restrict__ probs,
    int S)
{
    __shared__ float red[4];
    const int row = blockIdx.x;
    const unsigned short* p = scores + (size_t)row * S;
    unsigned short* pr      = probs  + (size_t)row * S;
    const int tid  = threadIdx.x;
    const int lane = tid & 63;
    const int wav  = tid >> 6;

    uint4 raw = *(const uint4*)(p + tid * 8);   // 8 bf16
    float v[8];
    v[0] = __uint_as_float(raw.x << 16); v[1] = __uint_as_float(raw.x & 0xffff0000u);
    v[2] = __uint_as_float(raw.y << 16); v[3] = __uint_as_float(raw.y & 0xffff0000u);
    v[4] = __uint_as_float(raw.z << 16); v[5] = __uint_as_float(raw.z & 0xffff0000u);
    v[6] = __uint_as_float(raw.w << 16); v[7] = __uint_as_float(raw.w & 0xffff0000u);

    float mx = v[0];
#pragma unroll
    for (int k = 1; k < 8; k++) mx = fmaxf(mx, v[k]);
#pragma unroll
    for (int off = 32; off > 0; off >>= 1) mx = fmaxf(mx, __shfl_down(mx, off));
    if (lane == 0) red[wav] = mx;
    __syncthreads();
    mx = fmaxf(fmaxf(red[0], red[1]), fmaxf(red[2], red[3]));
    __syncthreads();

    float s = 0.f;
#pragma unroll
    for (int k = 0; k < 8; k++) { v[k] = __expf(v[k] - mx); s += v[k]; }
#pragma unroll
    for (int off = 32; off > 0; off >>= 1) s += __shfl_down(s, off);
    if (lane == 0) red[wav] = s;
    __syncthreads();
    s = red[0] + red[1] + red[2] + red[3];
    float inv = 1.0f / s;

    uint4 o;
    o.x = (unsigned)f2bf(v[0] * inv) | ((unsigned)f2bf(v[1] * inv) << 16);
    o.y = (unsigned)f2bf(v[2] * inv) | ((unsigned)f2bf(v[3] * inv) << 16);
    o.z = (unsigned)f2bf(v[4] * inv) | ((unsigned)f2bf(v[5] * inv) << 16);
    o.w = (unsigned)f2bf(v[6] * inv) | ((unsigned)f2bf(v[7] * inv) << 16);
    *(uint4*)(pr + tid * 8) = o;
}

// ---------------------------------------------------------------------------
// out_row = LayerNorm(X_row)*g + b.  D = 1024. In-place safe (out == X).
// ---------------------------------------------------------------------------
template<int WRITE_BF16>
__global__ __launch_bounds__(256) void ln_kernel(
    const float* __restrict__ X,
    const float* __restrict__ g, const float* __restrict__ bta,
    float* __restrict__ out, unsigned short* __restrict__ out16, int D)
{
    __shared__ float red[8];
    const int row = blockIdx.x;
    const float* x = X + (size_t)row * D;
    const int tid  = threadIdx.x;
    const int lane = tid & 63;
    const int wav  = tid >> 6;

    float4 a = *(const float4*)(x + tid * 4);
    float v0 = a.x, v1 = a.y, v2 = a.z, v3 = a.w;

    float s1 = v0 + v1 + v2 + v3;
    float s2 = v0 * v0 + v1 * v1 + v2 * v2 + v3 * v3;
#pragma unroll
    for (int off = 32; off > 0; off >>= 1) {
        s1 += __shfl_down(s1, off);
        s2 += __shfl_down(s2, off);
    }
    if (lane == 0) { red[wav] = s1; red[4 + wav] = s2; }
    __syncthreads();
    s1 = red[0] + red[1] + red[2] + red[3];
    s2 = red[4] + red[5] + red[6] + red[7];
    const float mu  = s1 / (float)D;
    const float var = s2 / (float)D - mu * mu;
    const float rs  = rsqrtf(var + LN_EPS);

    float4 gg = *(const float4*)(g + tid * 4);
    float4 bb = *(const float4*)(bta + tid * 4);
    float4 r;
    r.x = (v0 - mu) * rs * gg.x + bb.x;
    r.y = (v1 - mu) * rs * gg.y + bb.y;
    r.z = (v2 - mu) * rs * gg.z + bb.z;
    r.w = (v3 - mu) * rs * gg.w + bb.w;
    *(float4*)(out + (size_t)row * D + tid * 4) = r;
    if (WRITE_BF16) {
        ushort4 h;
        h.x = f2bf(r.x); h.y = f2bf(r.y); h.z = f2bf(r.z); h.w = f2bf(r.w);
        *(ushort4*)(out16 + (size_t)row * D + tid * 4) = h;
    }
}

// ---------------------------------------------------------------------------
extern "C" void kernel_launch(void* const* d_in, const int* in_sizes, int n_in,
                              void* d_out, int out_size, void* d_ws, size_t ws_size,
                              hipStream_t stream) {
    (void)in_sizes; (void)n_in; (void)out_size; (void)ws_size;
    const float* x    = (const float*)d_in[0];
    const float* mask = (const float*)d_in[1];
    const float* w1   = (const float*)d_in[2];
    const float* b1   = (const float*)d_in[3];
    const float* w2   = (const float*)d_in[4];
    const float* b2   = (const float*)d_in[5];
    const float* ln1g = (const float*)d_in[6];
    const float* ln1b = (const float*)d_in[7];
    const float* ln2g = (const float*)d_in[8];
    const float* ln2b = (const float*)d_in[9];
    float* out = (float*)d_out;

    const int B = 4, S = 2048, D = 1024, DFF = 4096;
    const size_t MB = 1024 * 1024;

    // ws (128 MiB):
    //  [0,32M):   scoresb bf16 (1-2)         } act bf16 [0,64M) (5-6)
    //  [32,64M):  xb bf16 [32,48M) (prep-1), then probs bf16 (2-3)
    //  [64,96M):  hbuf fp32 = h (3-6)
    //  [96,112M): hb16 bf16 (4-5)
    //  [112,120M): w1T   [120,128M): w2T
    // d_out (32 MiB): xTb [0,16M) (prep-3); then fsum fp32 = h+ffn (6-7), LN in place.
    char* ws = (char*)d_ws;
    unsigned short* scoresb = (unsigned short*)ws;
    unsigned short* act     = (unsigned short*)ws;
    unsigned short* xb      = (unsigned short*)(ws + 32 * MB);
    unsigned short* probs   = (unsigned short*)(ws + 32 * MB);
    float*          hbuf    = (float*)(ws + 64 * MB);
    unsigned short* hb16    = (unsigned short*)(ws + 96 * MB);
    unsigned short* w1T     = (unsigned short*)(ws + 112 * MB);
    unsigned short* w2T     = (unsigned short*)(ws + 120 * MB);
    unsigned short* xTb     = (unsigned short*)d_out;
    float*          fsum    = (float*)d_out;

    // --- prep ---
    x_prep_kernel<<<dim3(D / 32, S / 32, B), 256, 0, stream>>>(
        x, xb, xTb, S, D, (long)S * D);
    transpose_cvt_kernel<<<dim3(DFF / 32, D / 32, 1), 256, 0, stream>>>(w1, w1T, D, DFF);
    transpose_cvt_kernel<<<dim3(D / 32, DFF / 32, 1), 256, 0, stream>>>(w2, w2T, DFF, D);

    // 1. scoresb[b] = (xb[b] @ xb[b]^T)*scale + mask  -> bf16
    hipLaunchKernelGGL((gemm_bt<3>), dim3(S / 128, S / 128, B), dim3(256), 0, stream,
                       xb, xb, mask, (const float*)nullptr, (void*)scoresb,
                       S, S, D, (long)S * D, (long)S * D, (long)S * S, (long)S, 0.03125f);
    // 2. probs = softmax(scoresb) -> bf16
    softmax_bf16_kernel<<<B * S, 256, 0, stream>>>(scoresb, probs, S);
    // 3. hbuf[b] = x[b] + probs[b] @ xTb[b]^T  -> fp32
    hipLaunchKernelGGL((gemm_bt<4>), dim3(D / 128, S / 128, B), dim3(256), 0, stream,
                       probs, xTb, (const float*)nullptr, x, (void*)hbuf,
                       S, D, S, (long)S * S, (long)D * S, (long)S * D, 0L, 0.f);
    // 4. h = LN(hbuf) in place + hb16 bf16
    hipLaunchKernelGGL((ln_kernel<1>), dim3(B * S), dim3(256), 0, stream,
                       hbuf, ln1g, ln1b, hbuf, hb16, D);
    // 5. act = gelu(h @ w1 + b1) -> bf16
    hipLaunchKernelGGL((gemm_bt<2>), dim3(DFF / 128, (B * S) / 128, 1), dim3(256), 0, stream,
                       hb16, w1T, b1, (const float*)nullptr, (void*)act,
                       B * S, DFF, D, 0L, 0L, 0L, 0L, 0.f);
    // 6. fsum = h + act @ w2 + b2 -> fp32 (into d_out)
    hipLaunchKernelGGL((gemm_bt<5>), dim3(D / 128, (B * S) / 128, 1), dim3(256), 0, stream,
                       act, w2T, b2, hbuf, (void*)fsum,
                       B * S, D, DFF, 0L, 0L, 0L, 0L, 0.f);
    // 7. out = LN(fsum) in place
    hipLaunchKernelGGL((ln_kernel<0>), dim3(B * S), dim3(256), 0, stream,
                       fsum, ln2g, ln2b, out, (unsigned short*)nullptr, D);
}